// Round 1
// baseline (221.415 us; speedup 1.0000x reference)
//
#include <hip/hip_runtime.h>

// YOLO-style loss on MI355X — round 5.
// pred:      [B, 8, 8, 8] f32   (B = 65536)
// label_rc:  [B, L, 2]    i32   (L = 16)
// label_box: [B, L, 3]    f32
// out:       [1] f32 = (coord + cond) / B
//
// R5: wave-autonomous design. R4 staged each 16-batch slice through LDS
// (32 KB + 4 KB owner table -> 4 blocks/CU occupancy cap, 3 barriers per
// block, full 128 MiB LDS round-trip). But one batch = 512 floats = exactly
// 64 lanes x 2 float4 -> a single wave holds the whole batch in registers:
//   - noobj: every float4's .w is a p3 or p7 -> accumulate on the fly.
//   - responsible-cell gather: cell c occupies float4 indices 2c, 2c+1,
//     held by lanes (2c&63), (2c&63)+1 in register c0 (c<32) or c1 (c>=32)
//     -> 16 __shfl (ds_bpermute), no LDS, no barrier.
//   - obj-mask dedup: owner election among the L=16 label lanes via a
//     16-step shfl scan (lowest lane with the same cell subtracts noobj).
// No LDS staging, no block barriers in the hot loop, no atomics ->
// full occupancy, pure coalesced streaming (each wave reads 8 consecutive
// batches = 16 KB contiguous, 1-deep register prefetch).

static constexpr float LAMBDA_COORD = 5.0f;
static constexpr float LAMBDA_NOOBJ = 0.5f;
static constexpr float EPS_F = 1e-9f;

#define WAVES_PER_BLOCK  4
#define BATCHES_PER_WAVE 8

__device__ __forceinline__ float bbox_iou(float px, float py, float pr,
                                          float gx, float gy, float gr) {
    float l1 = px - pr, r1 = px + pr, t1 = py - pr, b1 = py + pr;
    float l2 = gx - gr, r2 = gx + gr, t2 = gy - gr, b2 = gy + gr;
    float iw = fmaxf(fminf(r1, r2) - fmaxf(l1, l2), 0.0f);
    float ih = fmaxf(fminf(b1, b2) - fmaxf(t1, t2), 0.0f);
    float inter = iw * ih;
    float a1 = (r1 - l1) * (b1 - t1);
    float a2 = (r2 - l2) * (b2 - t2);
    return inter / (a1 + a2 - inter + EPS_F);
}

__global__ __launch_bounds__(256, 4) void yolo_loss_kernel(
    const float* __restrict__ pred,
    const int*   __restrict__ label_rc,
    const float* __restrict__ label_box,
    float* __restrict__ partials,
    int B, int L)
{
    const int tid  = threadIdx.x;
    const int lane = tid & 63;
    const int wv   = tid >> 6;

    const long wg      = (long)blockIdx.x * WAVES_PER_BLOCK + wv;
    const long b_begin = wg * BATCHES_PER_WAVE;
    long       b_end   = b_begin + BATCHES_PER_WAVE;
    if (b_end > (long)B) b_end = (long)B;

    const bool has_label = (lane < L);
    float acc = 0.0f;

    // 1-deep register prefetch of the wave's current batch (2 KB / batch).
    float4 v0, v1;
    if (b_begin < b_end) {
        const float4* gp = (const float4*)(pred + b_begin * 512);
        v0 = gp[lane];
        v1 = gp[lane + 64];
    }

    for (long b = b_begin; b < b_end; ++b) {
        const float4 c0 = v0, c1 = v1;
        if (b + 1 < b_end) {                    // prefetch next batch
            const float4* gp = (const float4*)(pred + (b + 1) * 512);
            v0 = gp[lane];
            v1 = gp[lane + 64];
        }

        // ---- labels: one (batch,label) per lane (lanes 0..L-1) ----
        int   cell = 0;
        float gx = 0.f, gy = 0.f, gr = 0.f;
        if (has_label) {
            const int2 rc = *(const int2*)(label_rc + ((size_t)b * L + lane) * 2);
            cell = rc.x * 8 + rc.y;             // 0..63
            const float* lb = label_box + ((size_t)b * L + lane) * 3;
            gx = lb[0]; gy = lb[1]; gr = lb[2];
        }

        // ---- noobj over all 64 cells (every .w is a p3 or p7) ----
        acc += LAMBDA_NOOBJ * (c0.w * c0.w + c1.w * c1.w);

        // ---- gather the responsible cell's 8 floats via shuffles ----
        // cell c -> float4 indices q=2c, q+1 (same half; q even).
        const int  q  = cell * 2;
        const bool lo = (q < 64);               // held in c0 (else c1)
        const int  sA = q & 63;
        const int  sB = sA + 1;

        float p0, p1, p2, p3, p4, p5, p6, p7;
        {   // both shuffles execute unconditionally (convergent), then select
            float a, bb;
            a = __shfl(c0.x, sA); bb = __shfl(c1.x, sA); p0 = lo ? a : bb;
            a = __shfl(c0.y, sA); bb = __shfl(c1.y, sA); p1 = lo ? a : bb;
            a = __shfl(c0.z, sA); bb = __shfl(c1.z, sA); p2 = lo ? a : bb;
            a = __shfl(c0.w, sA); bb = __shfl(c1.w, sA); p3 = lo ? a : bb;
            a = __shfl(c0.x, sB); bb = __shfl(c1.x, sB); p4 = lo ? a : bb;
            a = __shfl(c0.y, sB); bb = __shfl(c1.y, sB); p5 = lo ? a : bb;
            a = __shfl(c0.z, sB); bb = __shfl(c1.z, sB); p6 = lo ? a : bb;
            a = __shfl(c0.w, sB); bb = __shfl(c1.w, sB); p7 = lo ? a : bb;
        }

        // ---- obj-mask dedup: lowest label-lane with this cell owns it ----
        bool owner = has_label;
        for (int j = 0; j < L; ++j) {
            const int cj = __shfl(cell, j);     // broadcast (readlane)
            if (j < lane && cj == cell) owner = false;
        }

        // ---- per-label losses ----
        if (has_label) {
            const float iou1 = bbox_iou(p0, p1, p2, gx, gy, gr);
            const float iou2 = bbox_iou(p4, p5, p6, gx, gy, gr);
            const bool  sw   = iou2 > iou1;
            const float cx      = sw ? p4 : p0;
            const float cy      = sw ? p5 : p1;
            const float cr      = sw ? p6 : p2;
            const float conf    = sw ? p7 : p3;
            const float un_conf = sw ? p3 : p7;
            const float bigger  = sw ? iou2 : iou1;
            const float smaller = sw ? iou1 : iou2;
            const float dx = cx - gx, dy = cy - gy, dr = cr - gr;
            acc += LAMBDA_COORD * (dx * dx + dy * dy + dr * dr);
            const float d1 = bigger - conf;
            const float d2 = smaller - un_conf;
            acc += d1 * d1 + LAMBDA_NOOBJ * (d2 * d2);
            if (owner)                          // subtract labeled cell's noobj once
                acc -= LAMBDA_NOOBJ * (p3 * p3 + p7 * p7);
        }
    }

    // ---- wave + block reduction -> one partial per block ----
    #pragma unroll
    for (int off = 32; off > 0; off >>= 1)
        acc += __shfl_xor(acc, off);

    __shared__ float wsum[WAVES_PER_BLOCK];
    if (lane == 0) wsum[wv] = acc;
    __syncthreads();
    if (tid == 0)
        partials[blockIdx.x] = wsum[0] + wsum[1] + wsum[2] + wsum[3];
}

__global__ __launch_bounds__(256) void reduce_kernel(
    const float* __restrict__ partials, float* __restrict__ out,
    int n, float invB)
{
    float s = 0.0f;
    for (int i = threadIdx.x; i < n; i += 256)
        s += partials[i];
    #pragma unroll
    for (int off = 32; off > 0; off >>= 1)
        s += __shfl_xor(s, off);

    __shared__ float wsum[4];
    const int lane = threadIdx.x & 63, w = threadIdx.x >> 6;
    if (lane == 0) wsum[w] = s;
    __syncthreads();
    if (threadIdx.x == 0)
        out[0] = (wsum[0] + wsum[1] + wsum[2] + wsum[3]) * invB;
}

extern "C" void kernel_launch(void* const* d_in, const int* in_sizes, int n_in,
                              void* d_out, int out_size, void* d_ws, size_t ws_size,
                              hipStream_t stream) {
    const float* pred      = (const float*)d_in[0];
    const int*   label_rc  = (const int*)d_in[1];
    const float* label_box = (const float*)d_in[2];
    float*       out       = (float*)d_out;
    float*       partials  = (float*)d_ws;

    const int B = in_sizes[0] / 512;          // G*G*C = 8*8*8
    const int L = in_sizes[1] / (B * 2);      // labels per batch (16)
    const float invB = 1.0f / (float)B;

    const int batches_per_block = WAVES_PER_BLOCK * BATCHES_PER_WAVE;   // 32
    const int blocks = (B + batches_per_block - 1) / batches_per_block; // 2048

    yolo_loss_kernel<<<blocks, 256, 0, stream>>>(
        pred, label_rc, label_box, partials, B, L);

    reduce_kernel<<<1, 256, 0, stream>>>(partials, out, blocks, invB);
}

// Round 2
// 206.290 us; speedup vs baseline: 1.0733x; 1.0733x over previous
//
#include <hip/hip_runtime.h>

// YOLO-style loss on MI355X — round 6.
// pred:      [B, 8, 8, 8] f32   (B = 65536)
// label_rc:  [B, L, 2]    i32   (L = 16)
// label_box: [B, L, 3]    f32
// out:       [1] f32 = (coord + cond) / B
//
// R6: R5's wave-autonomous shuffle design was issue/latency-bound (77.5 us,
// 12.5% HBM, VALUBusy 26%): ~32 ds_bpermute + ~300 VALU per batch, IoU math
// on only 16/64 lanes, serial shfl owner election. R6 removes all of it:
//   - 4 batches per super-iteration: lane group g (16 lanes) handles batch
//     b0+g's 16 labels -> 100% lane utilization on the loss math.
//   - gather via wave-PRIVATE LDS staging (2 ds_write_b128 + 2 ds_read_b128
//     per batch, no barrier: same-wave LDS ops execute in order).
//   - obj-mask dedup: ONE ds_or_rtn_b32 per label on a per-(wave,batch)
//     LDS mask word; old value tells the owner (first setter) who subtracts
//     that cell's noobj term once. No election loop.
// Per batch: ~3 DS + ~30 VALU (was ~34 DS + ~378 VALU). 8 dwordx4 loads in
// flight per wave per super-iter -> memory-level parallelism to reach the
// HBM roofline (~25 us for 155 MB).

static constexpr float LAMBDA_COORD = 5.0f;
static constexpr float LAMBDA_NOOBJ = 0.5f;
static constexpr float EPS_F = 1e-9f;

#define WAVES_PER_BLOCK 4
#define SUPER  4          // batches per super-iteration (one per 16-lane group)
#define SUPERS 2          // super-iterations per wave -> 8 batches/wave, 32/block

__device__ __forceinline__ float bbox_iou(float px, float py, float pr,
                                          float gx, float gy, float gr) {
    float l1 = px - pr, r1 = px + pr, t1 = py - pr, b1 = py + pr;
    float l2 = gx - gr, r2 = gx + gr, t2 = gy - gr, b2 = gy + gr;
    float iw = fmaxf(fminf(r1, r2) - fmaxf(l1, l2), 0.0f);
    float ih = fmaxf(fminf(b1, b2) - fmaxf(t1, t2), 0.0f);
    float inter = iw * ih;
    float a1 = (r1 - l1) * (b1 - t1);
    float a2 = (r2 - l2) * (b2 - t2);
    return inter / (a1 + a2 - inter + EPS_F);
}

// Load one super-iteration's 4 batches (2 float4 per lane per batch).
#define LOAD_SUPER(dst, b0)                                                    \
    {                                                                          \
        _Pragma("unroll")                                                      \
        for (int q = 0; q < SUPER; ++q) {                                      \
            const long b_ = (b0) + q;                                          \
            if (b_ < (long)B) {                                                \
                const float4* gp_ = (const float4*)(pred + b_ * 512);          \
                dst[2 * q]     = gp_[lane];                                    \
                dst[2 * q + 1] = gp_[lane + 64];                               \
            } else {                                                           \
                dst[2 * q]     = make_float4(0.f, 0.f, 0.f, 0.f);              \
                dst[2 * q + 1] = make_float4(0.f, 0.f, 0.f, 0.f);              \
            }                                                                  \
        }                                                                      \
    }

// Process one super-iteration: stage to LDS, noobj accumulate, per-label loss.
#define PROC_SUPER(buf, b0)                                                    \
    {                                                                          \
        /* reset the 8 per-batch mask words (lanes 0..7) */                    \
        if (lane < SUPER * 2) my_mask[lane] = 0u;                              \
        _Pragma("unroll")                                                      \
        for (int q = 0; q < SUPER; ++q) {                                      \
            noobj_acc += buf[2 * q].w     * buf[2 * q].w                       \
                       + buf[2 * q + 1].w * buf[2 * q + 1].w;                  \
            float4* sp4_ = (float4*)(my_stage + q * 512);                      \
            sp4_[lane]      = buf[2 * q];                                      \
            sp4_[lane + 64] = buf[2 * q + 1];                                  \
        }                                                                      \
        asm volatile("s_waitcnt lgkmcnt(0)" ::: "memory");                     \
        const long bq_ = (b0) + grp;                                           \
        if (bq_ < (long)B && lj < L) {                                         \
            const int2 rc_ = *(const int2*)(label_rc + ((size_t)bq_ * L + lj) * 2); \
            const float* lb_ = label_box + ((size_t)bq_ * L + lj) * 3;         \
            const float gx = lb_[0], gy = lb_[1], gr = lb_[2];                 \
            const int cell_ = rc_.x * 8 + rc_.y;                               \
            const float4* cp_ = (const float4*)(my_stage + grp * 512 + cell_ * 8); \
            const float4 c0_ = cp_[0];                                         \
            const float4 c1_ = cp_[1];                                         \
            const unsigned bit_ = 1u << (cell_ & 31);                          \
            const unsigned old_ = atomicOr(&my_mask[grp * 2 + (cell_ >> 5)], bit_); \
            const float p0 = c0_.x, p1 = c0_.y, p2 = c0_.z, p3 = c0_.w;        \
            const float p4 = c1_.x, p5 = c1_.y, p6 = c1_.z, p7 = c1_.w;        \
            const float iou1 = bbox_iou(p0, p1, p2, gx, gy, gr);               \
            const float iou2 = bbox_iou(p4, p5, p6, gx, gy, gr);               \
            const bool  sw_ = iou2 > iou1;                                     \
            const float cx = sw_ ? p4 : p0;                                    \
            const float cy = sw_ ? p5 : p1;                                    \
            const float cr = sw_ ? p6 : p2;                                    \
            const float conf    = sw_ ? p7 : p3;                               \
            const float un_conf = sw_ ? p3 : p7;                               \
            const float bigger  = sw_ ? iou2 : iou1;                           \
            const float smaller = sw_ ? iou1 : iou2;                           \
            const float dx = cx - gx, dy = cy - gy, dr = cr - gr;              \
            main_acc += LAMBDA_COORD * (dx * dx + dy * dy + dr * dr);          \
            const float d1 = bigger - conf;                                    \
            main_acc += d1 * d1;                                               \
            const float d2 = smaller - un_conf;                                \
            noobj_acc += d2 * d2;                                              \
            if ((old_ & bit_) == 0u)      /* owner: subtract labeled cell */   \
                noobj_acc -= (p3 * p3 + p7 * p7);                              \
        }                                                                      \
    }

__global__ __launch_bounds__(256, 4) void yolo_loss_kernel(
    const float* __restrict__ pred,
    const int*   __restrict__ label_rc,
    const float* __restrict__ label_box,
    float* __restrict__ partials,
    int B, int L)
{
    __shared__ float    stage[WAVES_PER_BLOCK][SUPER * 512];   // 32 KB
    __shared__ unsigned cmask[WAVES_PER_BLOCK][SUPER * 2];     // 128 B
    __shared__ float    wsum[WAVES_PER_BLOCK];

    const int tid  = threadIdx.x;
    const int lane = tid & 63;
    const int wv   = tid >> 6;
    const int grp  = lane >> 4;     // which batch of the super-iteration
    const int lj   = lane & 15;     // label index within that batch

    float*    my_stage = stage[wv];
    unsigned* my_mask  = cmask[wv];

    const long b_base =
        ((long)blockIdx.x * WAVES_PER_BLOCK + wv) * (SUPER * SUPERS);

    float main_acc  = 0.0f;  // lambda_coord * coord + d1^2
    float noobj_acc = 0.0f;  // sum w^2 - owner(p3^2+p7^2) + d2^2 (x lambda_noobj at end)

    // Software pipeline: both super-iterations' pred loads issued up front
    // (16 dwordx4 in flight per wave), then consume in order.
    float4 bufA[2 * SUPER];
    float4 bufB[2 * SUPER];
    LOAD_SUPER(bufA, b_base);
    LOAD_SUPER(bufB, b_base + SUPER);

    PROC_SUPER(bufA, b_base);
    PROC_SUPER(bufB, b_base + SUPER);

    // ---- wave + block reduction -> one partial per block ----
    float acc = main_acc + LAMBDA_NOOBJ * noobj_acc;
    #pragma unroll
    for (int off = 32; off > 0; off >>= 1)
        acc += __shfl_xor(acc, off);
    if (lane == 0) wsum[wv] = acc;
    __syncthreads();
    if (tid == 0)
        partials[blockIdx.x] = wsum[0] + wsum[1] + wsum[2] + wsum[3];
}

__global__ __launch_bounds__(256) void reduce_kernel(
    const float* __restrict__ partials, float* __restrict__ out,
    int n, float invB)
{
    float s = 0.0f;
    for (int i = threadIdx.x; i < n; i += 256)
        s += partials[i];
    #pragma unroll
    for (int off = 32; off > 0; off >>= 1)
        s += __shfl_xor(s, off);

    __shared__ float wsum[4];
    const int lane = threadIdx.x & 63, w = threadIdx.x >> 6;
    if (lane == 0) wsum[w] = s;
    __syncthreads();
    if (threadIdx.x == 0)
        out[0] = (wsum[0] + wsum[1] + wsum[2] + wsum[3]) * invB;
}

extern "C" void kernel_launch(void* const* d_in, const int* in_sizes, int n_in,
                              void* d_out, int out_size, void* d_ws, size_t ws_size,
                              hipStream_t stream) {
    const float* pred      = (const float*)d_in[0];
    const int*   label_rc  = (const int*)d_in[1];
    const float* label_box = (const float*)d_in[2];
    float*       out       = (float*)d_out;
    float*       partials  = (float*)d_ws;

    const int B = in_sizes[0] / 512;          // G*G*C = 8*8*8
    const int L = in_sizes[1] / (B * 2);      // labels per batch (16)
    const float invB = 1.0f / (float)B;

    const int batches_per_block = WAVES_PER_BLOCK * SUPER * SUPERS;     // 32
    const int blocks = (B + batches_per_block - 1) / batches_per_block; // 2048

    yolo_loss_kernel<<<blocks, 256, 0, stream>>>(
        pred, label_rc, label_box, partials, B, L);

    reduce_kernel<<<1, 256, 0, stream>>>(partials, out, blocks, invB);
}